// Round 1
// baseline (13224.806 us; speedup 1.0000x reference)
//
#include <hip/hip_runtime.h>
#include <cstdint>
#include <cstddef>

typedef __bf16 bf16;
typedef float f32x4 __attribute__((ext_vector_type(4)));
typedef bf16 bf16x8 __attribute__((ext_vector_type(8)));
typedef bf16 bf16x4 __attribute__((ext_vector_type(4)));

#define AS1 __attribute__((address_space(1)))
#define AS3 __attribute__((address_space(3)))

__device__ __forceinline__ void gload_lds16(const void* g, void* l) {
  // async global->LDS, 16B per lane; LDS dest must be wave-uniform base + lane*16
  __builtin_amdgcn_global_load_lds((AS1 void*)g, (AS3 void*)l, 16, 0, 0);
}

// ---------------- init: combined biases + barrier counters ----------------
__global__ __launch_bounds__(256) void init_misc(
    const float* __restrict__ bih0, const float* __restrict__ bhh0,
    const float* __restrict__ bih1, const float* __restrict__ bhh1,
    float* __restrict__ bsum0, float* __restrict__ bsum1, unsigned* __restrict__ cnts) {
  int i = blockIdx.x * 256 + threadIdx.x;
  if (i < 4096) {
    bsum0[i] = bih0[i] + bhh0[i];
    bsum1[i] = bih1[i] + bhh1[i];
  }
  if (i < 64) cnts[i] = 0u;
}

// ---------------- embedding gather -> bf16, row = t*16 + b ----------------
__global__ __launch_bounds__(256) void embed_gather(
    const int* __restrict__ x, const float* __restrict__ emb, bf16* __restrict__ xe, int T) {
  int row = blockIdx.x;           // t*16 + b
  int t = row >> 4, b = row & 15;
  int tok = x[b * T + t];
  int cix = threadIdx.x << 2;     // 4 floats per thread (1024 cols / 256 thr)
  f32x4 v = *(const f32x4*)(emb + ((size_t)tok << 10) + cix);
  bf16x4 o;
  for (int j = 0; j < 4; ++j) o[j] = (bf16)v[j];
  *(bf16x4*)(xe + ((size_t)row << 10) + cix) = o;
}

// ---------------- GEMM: C[M,N] = A[M,K](bf16) * W[N,K](f32->bf16)^T + bias ----------------
// 128x128 tile, BK=32, 4 waves each 64x64. A via global_load_lds (swizzled src),
// B reg-staged f32->bf16 with swizzled ds_write. OUTMODE 0: C row-major [M][N].
// OUTMODE 1: row r=(t*16+b) scattered to C[(b*Tdim + t)*N + col] (logits [B,T,V]).
template <int OUTMODE>
__global__ __launch_bounds__(256) void gemm_bf16(
    const bf16* __restrict__ A, const float* __restrict__ Bw,
    const float* __restrict__ bias, float* __restrict__ C,
    int M, int N, int K, int Tdim) {
  __shared__ bf16 aL[2][128 * 32];
  __shared__ bf16 bL[2][128 * 32];
  const int tid = threadIdx.x;
  const int l = tid & 63, w = tid >> 6;
  const int nbm = M >> 7;
  const int bm = blockIdx.x % nbm;
  const int bn = blockIdx.x / nbm;
  const int wr = (w >> 1) << 6, wc = (w & 1) << 6;
  const int NT = K >> 5;
  const int r16 = l & 15, kq = l >> 4;

  f32x4 acc[4][4];
  for (int m = 0; m < 4; ++m)
    for (int n = 0; n < 4; ++n) acc[m][n] = (f32x4){0.f, 0.f, 0.f, 0.f};

  // prologue: stage kt=0 into buffer 0
  for (int i = 0; i < 2; ++i) {
    int lin = tid + (i << 8);
    int r = lin >> 2, s = lin & 3, c = s ^ (r & 3);
    gload_lds16(A + (size_t)((bm << 7) + r) * K + (c << 3), &aL[0][lin << 3]);
  }
  for (int i = 0; i < 2; ++i) {
    int lin = tid + (i << 8);
    int r = lin >> 2, c = lin & 3;
    const float* src = Bw + (size_t)((bn << 7) + r) * K + (c << 3);
    f32x4 v0 = *(const f32x4*)src;
    f32x4 v1 = *(const f32x4*)(src + 4);
    bf16x8 o;
    for (int j = 0; j < 4; ++j) { o[j] = (bf16)v0[j]; o[j + 4] = (bf16)v1[j]; }
    *(bf16x8*)&bL[0][(r << 5) + ((c ^ (r & 3)) << 3)] = o;
  }
  __syncthreads();

  for (int kt = 0; kt < NT; ++kt) {
    const int cur = kt & 1;
    const bool pf = (kt + 1 < NT);
    f32x4 bv0[2], bv1[2];
    int br_[2], bs_[2];
    if (pf) {
      for (int i = 0; i < 2; ++i) {
        int lin = tid + (i << 8);
        int r = lin >> 2, s = lin & 3, c = s ^ (r & 3);
        gload_lds16(A + (size_t)((bm << 7) + r) * K + ((kt + 1) << 5) + (c << 3),
                    &aL[cur ^ 1][lin << 3]);
      }
      for (int i = 0; i < 2; ++i) {
        int lin = tid + (i << 8);
        int r = lin >> 2, c = lin & 3;
        const float* src = Bw + (size_t)((bn << 7) + r) * K + ((kt + 1) << 5) + (c << 3);
        bv0[i] = *(const f32x4*)src;
        bv1[i] = *(const f32x4*)(src + 4);
        br_[i] = r;
        bs_[i] = c ^ (r & 3);
      }
    }
    // compute current buffer
    bf16x8 af[4], bfr[4];
    for (int m = 0; m < 4; ++m) {
      int row = wr + (m << 4) + r16;
      int ch = kq ^ (row & 3);
      af[m] = *(const bf16x8*)&aL[cur][(row << 5) + (ch << 3)];
    }
    for (int n = 0; n < 4; ++n) {
      int row = wc + (n << 4) + r16;
      int ch = kq ^ (row & 3);
      bfr[n] = *(const bf16x8*)&bL[cur][(row << 5) + (ch << 3)];
    }
    for (int m = 0; m < 4; ++m)
      for (int n = 0; n < 4; ++n)
        acc[m][n] = __builtin_amdgcn_mfma_f32_16x16x32_bf16(af[m], bfr[n], acc[m][n], 0, 0, 0);
    if (pf) {
      for (int i = 0; i < 2; ++i) {
        bf16x8 o;
        for (int j = 0; j < 4; ++j) { o[j] = (bf16)bv0[i][j]; o[j + 4] = (bf16)bv1[i][j]; }
        *(bf16x8*)&bL[cur ^ 1][(br_[i] << 5) + (bs_[i] << 3)] = o;
      }
    }
    __syncthreads();
  }

  // epilogue: C[row][col], row = wr+m*16+kq*4+r, col = wc+n*16+r16 (+bias)
  float bvv[4];
  for (int n = 0; n < 4; ++n) bvv[n] = bias[(bn << 7) + wc + (n << 4) + r16];
  for (int m = 0; m < 4; ++m) {
    int Rbase = (bm << 7) + wr + (m << 4) + (kq << 2);
    for (int r = 0; r < 4; ++r) {
      int R = Rbase + r;
      size_t rowoff;
      if (OUTMODE == 0) {
        rowoff = (size_t)R * N;
      } else {
        int tt = R >> 4, bb = R & 15;
        rowoff = ((size_t)bb * Tdim + tt) * N;
      }
      for (int n = 0; n < 4; ++n)
        C[rowoff + (bn << 7) + wc + (n << 4) + r16] = acc[m][n][r] + bvv[n];
    }
  }
}

// ---------------- persistent LSTM recurrence ----------------
// 64 blocks x 256 thr. Block owns 16 H-cols (all 4 gates = 64 Whh rows),
// Whh slice f32->bf16 XOR-swizzled in LDS (128KB). Per step: wave g computes
// gate g's [16b x 16j] via MFMA over K=1024, gate fusion per-thread (c in reg),
// h -> hs[t] bf16, then device-scope grid barrier.
__global__ __launch_bounds__(256) void lstm_rec(
    const float* __restrict__ gx,   // [T*16][4096]
    const float* __restrict__ Whh,  // [4096][1024] f32
    bf16* __restrict__ hs,          // [T*16][1024] out (also h history)
    unsigned* __restrict__ counter, int T) {
  __shared__ bf16 whh[64 * 1024];      // 128 KiB, swizzled
  __shared__ float glds[4 * 16 * 16];  // 4 KiB gate exchange
  const int tid = threadIdx.x;
  const int l = tid & 63, w = tid >> 6;
  const int j0 = blockIdx.x << 4;
  const int G = gridDim.x;

  // stage Whh slice: 64 rows (g*16+n) x 1024, chunk swizzle cs = c ^ (row&7)
  for (int it = 0; it < 32; ++it) {
    int lin = tid + (it << 8);  // 16B-chunk id, 0..8191
    int row = lin >> 7;         // 0..63
    int cs = lin & 127;         // dest slot
    int c = cs ^ (row & 7);     // source chunk
    int g = row >> 4, n = row & 15;
    const float* src = Whh + (size_t)(g * 1024 + j0 + n) * 1024 + (c << 3);
    f32x4 v0 = *(const f32x4*)src;
    f32x4 v1 = *(const f32x4*)(src + 4);
    bf16x8 o;
    for (int j = 0; j < 4; ++j) { o[j] = (bf16)v0[j]; o[j + 4] = (bf16)v1[j]; }
    *(bf16x8*)(whh + (row << 10) + (cs << 3)) = o;
  }
  __syncthreads();

  const int bidx = tid >> 4, jl = tid & 15;
  const int r16 = l & 15, kq = l >> 4;
  const int rx = r16 & 7;
  float cst = 0.f;

  for (int t = 0; t < T; ++t) {
    f32x4 acc = (f32x4){0.f, 0.f, 0.f, 0.f};
    if (t > 0) {
      const bf16* hp = hs + ((size_t)(t - 1) << 14) + (r16 << 10) + (kq << 3);
      const bf16* wb = whh + ((w << 4) + r16) * 1024;
#pragma unroll 8
      for (int kk = 0; kk < 32; ++kk) {
        bf16x8 a = *(const bf16x8*)(hp + (kk << 5));
        int ch = ((kk << 2) + kq) ^ rx;
        bf16x8 bb = *(const bf16x8*)(wb + (ch << 3));
        acc = __builtin_amdgcn_mfma_f32_16x16x32_bf16(a, bb, acc, 0, 0, 0);
      }
    }
    for (int r = 0; r < 4; ++r) glds[(w << 8) + (((kq << 2) + r) << 4) + r16] = acc[r];
    __syncthreads();

    const float* gp = gx + (((size_t)t * 16 + bidx) << 12) + j0 + jl;
    float xi = glds[(bidx << 4) + jl] + gp[0];
    float xf = glds[256 + (bidx << 4) + jl] + gp[1024];
    float xg = glds[512 + (bidx << 4) + jl] + gp[2048];
    float xo = glds[768 + (bidx << 4) + jl] + gp[3072];
    float ig = 1.f / (1.f + __expf(-xi));
    float fg = 1.f / (1.f + __expf(-xf));
    float eg = __expf(2.f * xg);
    float gg = 1.f - 2.f / (eg + 1.f);
    float og = 1.f / (1.f + __expf(-xo));
    cst = fg * cst + ig * gg;
    float ec = __expf(2.f * cst);
    float th = 1.f - 2.f / (ec + 1.f);
    hs[(((size_t)t * 16 + bidx) << 10) + j0 + jl] = (bf16)(og * th);

    // grid barrier: release writes, arrive, spin, acquire
    __threadfence();
    __syncthreads();
    if (tid == 0) {
      __hip_atomic_fetch_add(counter, 1u, __ATOMIC_RELEASE, __HIP_MEMORY_SCOPE_AGENT);
      unsigned tgt = (unsigned)G * (unsigned)(t + 1);
      while (__hip_atomic_load(counter, __ATOMIC_RELAXED, __HIP_MEMORY_SCOPE_AGENT) < tgt)
        __builtin_amdgcn_s_sleep(8);
      (void)__hip_atomic_load(counter, __ATOMIC_ACQUIRE, __HIP_MEMORY_SCOPE_AGENT);
    }
    __syncthreads();
  }
}

extern "C" void kernel_launch(void* const* d_in, const int* in_sizes, int n_in,
                              void* d_out, int out_size, void* d_ws, size_t ws_size,
                              hipStream_t stream) {
  const int* x = (const int*)d_in[0];
  const float* emb = (const float*)d_in[1];
  const float* Wih0 = (const float*)d_in[2];
  const float* Whh0 = (const float*)d_in[3];
  const float* bih0 = (const float*)d_in[4];
  const float* bhh0 = (const float*)d_in[5];
  const float* Wih1 = (const float*)d_in[6];
  const float* Whh1 = (const float*)d_in[7];
  const float* bih1 = (const float*)d_in[8];
  const float* bhh1 = (const float*)d_in[9];
  const float* Wout = (const float*)d_in[10];
  const float* bout = (const float*)d_in[11];

  const int T = 512, H = 1024, V = 32000;
  const int M = T * 16;                   // 8192 rows (t-major, b minor)
  const size_t bfb = (size_t)M * H * 2;   // 16 MiB bf16 plane

  // workspace layout (hs1 must NOT live in d_out: projection reads it while writing d_out)
  char* p = (char*)d_ws;
  bf16* hs1 = (bf16*)p;           p += bfb;
  float* bsum0 = (float*)p;       p += 4096 * 4;
  float* bsum1 = (float*)p;       p += 4096 * 4;
  unsigned* cnts = (unsigned*)p;  p += 256;
  size_t base_need = (size_t)(p - (char*)d_ws);
  bf16 *xe, *hs0;
  if (ws_size >= base_need + 2 * bfb) {
    xe = (bf16*)p;
    hs0 = (bf16*)(p + bfb);
  } else {  // fall back to d_out tail (dead before projection writes it)
    char* tail = (char*)d_out + (size_t)out_size * 4 - 2 * bfb;
    xe = (bf16*)tail;
    hs0 = (bf16*)(tail + bfb);
  }
  float* gx = (float*)d_out;  // 134 MB scratch at head of d_out (dead before projection)

  init_misc<<<16, 256, 0, stream>>>(bih0, bhh0, bih1, bhh1, bsum0, bsum1, cnts);
  embed_gather<<<M, 256, 0, stream>>>(x, emb, xe, T);
  gemm_bf16<0><<<(M / 128) * (4096 / 128), 256, 0, stream>>>(xe, Wih0, bsum0, gx, M, 4096, H, 0);
  lstm_rec<<<64, 256, 0, stream>>>(gx, Whh0, hs0, cnts + 0, T);
  gemm_bf16<0><<<(M / 128) * (4096 / 128), 256, 0, stream>>>(hs0, Wih1, bsum1, gx, M, 4096, H, 0);
  lstm_rec<<<64, 256, 0, stream>>>(gx, Whh1, hs1, cnts + 16, T);
  gemm_bf16<1><<<(M / 128) * (V / 128), 256, 0, stream>>>(hs1, Wout, bout, (float*)d_out, M, V, H, T);
}